// Round 1
// baseline (57.068 us; speedup 1.0000x reference)
//
#include <hip/hip_runtime.h>

#define D_MAX   50
#define T_DIM   51          // D_MAX + 1
#define B_DIM   16
#define P_DIM   2048
#define Q_DIM   2048
#define TPAD    64          // padded T so each (p,b) row is 512B-aligned
#define PCHUNK  32
#define NCHUNK  (P_DIM / PCHUNK)   // 64

// ws layout:
//   bufT2  : float2 [P][B][TPAD]        = 2048*16*64*8  = 16 MiB
//   partial: float  [NCHUNK][B][Q]      = 64*16*2048*4  =  8 MiB

// Kernel 1: buf [B][T][P] -> bufT2 [P][B][TPAD] of (v[t], v[t+1]) pairs, zero-padded.
__global__ __launch_bounds__(256) void dsl_transpose_kernel(
    const float* __restrict__ buf, float2* __restrict__ bufT2) {
    __shared__ float lds[T_DIM][33];   // +1 pad -> conflict-free column reads
    const int p0 = blockIdx.x * 32;
    const int b  = blockIdx.y;
    const int tid = threadIdx.x;

    // load phase: rows t, 32 consecutive p per row (coalesced 128B segments)
    const int pp = tid & 31, tt = tid >> 5;
    for (int t = tt; t < T_DIM; t += 8)
        lds[t][pp] = buf[((size_t)(b * T_DIM + t)) * P_DIM + p0 + pp];
    __syncthreads();

    // store phase: for each p, write 64 consecutive float2 (512B, coalesced)
    const int t2 = tid & 63, pr0 = tid >> 6;
    for (int pr = pr0; pr < 32; pr += 4) {
        float v0 = (t2 < T_DIM)     ? lds[t2][pr]     : 0.f;
        float v1 = (t2 + 1 < T_DIM) ? lds[t2 + 1][pr] : 0.f;
        bufT2[((size_t)(p0 + pr) * B_DIM + b) * TPAD + t2] = make_float2(v0, v1);
    }
}

// Kernel 2: per-thread q, 16 batch accumulators, p-chunk reduction.
__global__ __launch_bounds__(256) void dsl_main_kernel(
    const float* __restrict__ W, const float* __restrict__ DR,
    const float2* __restrict__ bufT2, float* __restrict__ partial) {
    const int q  = blockIdx.x * 256 + threadIdx.x;
    const int p0 = blockIdx.y * PCHUNK;

    float acc[B_DIM];
#pragma unroll
    for (int b = 0; b < B_DIM; ++b) acc[b] = 0.f;

    for (int p = p0; p < p0 + PCHUNK; ++p) {
        const float w = W[(size_t)p * Q_DIM + q];
        const float x = DR[(size_t)p * Q_DIM + q];
        // d = D_MAX * sigmoid(x) in [0, 50]
        const float d = 50.f / (1.f + __expf(-x));
        int df = (int)d;              // == floor(d), d >= 0
        df = min(df, D_MAX);
        const float a   = d - (float)df;
        const float wa  = w * a;      // fold alpha into weight:
        const float wna = w - wa;     // acc += wna*s_f + wa*s_c

        const float2* row = bufT2 + (size_t)p * B_DIM * TPAD + df;
#pragma unroll
        for (int b = 0; b < B_DIM; ++b) {
            const float2 s = row[b * TPAD];   // (buf[t], buf[t+1]) in one 8B gather
            acc[b] = fmaf(wna, s.x, fmaf(wa, s.y, acc[b]));
        }
    }

    float* dst = partial + (size_t)blockIdx.y * B_DIM * Q_DIM + q;
#pragma unroll
    for (int b = 0; b < B_DIM; ++b)
        dst[(size_t)b * Q_DIM] = acc[b];
}

// Kernel 3: sum the NCHUNK partials.
__global__ __launch_bounds__(256) void dsl_reduce_kernel(
    const float* __restrict__ partial, float* __restrict__ out) {
    const int idx = blockIdx.x * 256 + threadIdx.x;   // idx = b*Q + q
    float s = 0.f;
    for (int c = 0; c < NCHUNK; ++c)
        s += partial[(size_t)c * (B_DIM * Q_DIM) + idx];
    out[idx] = s;
}

extern "C" void kernel_launch(void* const* d_in, const int* in_sizes, int n_in,
                              void* d_out, int out_size, void* d_ws, size_t ws_size,
                              hipStream_t stream) {
    const float* buf = (const float*)d_in[0];   // [B, T, P]
    const float* W   = (const float*)d_in[1];   // [P, Q]
    const float* DR  = (const float*)d_in[2];   // [P, Q]
    float* out = (float*)d_out;                 // [B, Q]

    char* ws = (char*)d_ws;
    float2* bufT2  = (float2*)ws;
    float* partial = (float*)(ws + (size_t)P_DIM * B_DIM * TPAD * sizeof(float2));

    hipLaunchKernelGGL(dsl_transpose_kernel, dim3(P_DIM / 32, B_DIM), dim3(256), 0, stream,
                       buf, bufT2);
    hipLaunchKernelGGL(dsl_main_kernel, dim3(Q_DIM / 256, NCHUNK), dim3(256), 0, stream,
                       W, DR, bufT2, partial);
    hipLaunchKernelGGL(dsl_reduce_kernel, dim3((B_DIM * Q_DIM) / 256), dim3(256), 0, stream,
                       partial, out);
}